// Round 12
// baseline (285.717 us; speedup 1.0000x reference)
//
#include <hip/hip_runtime.h>

// FindInstancePeaks: fused conv backbone + global peak finding.
// crops (128,192,192,1) f32 -> conv1 3x3 s2 SAME (1->32) + relu
//                          -> conv2 3x3 s1 SAME (32->17) = cms (128,96,96,17)
// -> per (b,n): argmax over 96x96, quarter-pixel sign refine, *2, NaN<0.2.
//
// R12 = R11 with the repack grid bug fixed (19 blocks covered only 4864 of
// 4896 elements -> last 32 weights were zeros -> wrong peaks). Design:
//  (1) W2 repacked [k][c][n] -> [c][k][n] into a device global: per (g,cl)
//      the 153 weight floats are contiguous, so the k-rotated s_load
//      prefetch becomes tight hoistable clumps instead of 9 scattered
//      2176B-strided groups that re-miss the scalar cache.
//  (2) argmax epilogue: 32-bit fmax butterfly + ballot/ffs lowest-lane pick
//      (lane->flat monotone within wave) instead of 64-bit packed
//      butterfly; packed-u64 atomic keeps exact global argmax semantics.

#define NCH 17
#define C1 32
#define TS2 32          // cms tile (32x32)
#define HT2 34          // h rows/cols needed (tile+2)
#define HS 36           // s_h col stride (floats): 144 B rows, 16B-aligned
#define IN2 69          // input patch: 2*32+5
#define CG 4            // conv1 channels per group
#define NG 8            // groups
#define KSTRIDE 153     // 9*17 floats per channel in packed W2

__device__ float w2pack[C1 * KSTRIDE];   // [c][k][n]

__device__ __forceinline__ unsigned long long pack_key(float v, unsigned flat) {
    unsigned ub = __float_as_uint(v);
    ub = (ub & 0x80000000u) ? ~ub : (ub | 0x80000000u);   // monotone float->uint
    return ((unsigned long long)ub << 32) | (unsigned)(~flat); // ~flat: ties -> lowest idx
}

__global__ void repack_kernel(const float* __restrict__ W2g) {
    int i = blockIdx.x * 256 + threadIdx.x;
    if (i < 9 * C1 * NCH) {
        int k = i / (C1 * NCH);
        int r = i - k * (C1 * NCH);
        int c = r / NCH, n = r - c * NCH;
        w2pack[c * KSTRIDE + k * NCH + n] = W2g[i];
    }
}

__global__ __launch_bounds__(256, 4) void conv_peaks_kernel(
    const float* __restrict__ crops, const float* __restrict__ W1g,
    const float* __restrict__ b1g, const float* __restrict__ b2g,
    unsigned long long* __restrict__ peaks) {
    __shared__ float s_in[IN2 * IN2];                        // 19044 B
    __shared__ __align__(16) float s_h[CG * HT2 * HS];       // 19584 B

    const int t = threadIdx.x;
    const int b = blockIdx.y;
    const int ty0 = (blockIdx.x / 3) * TS2;
    const int tx0 = (blockIdx.x % 3) * TS2;
    const int iy0 = 2 * ty0 - 2;
    const int ix0 = 2 * tx0 - 2;
    const float* cb = crops + b * 192 * 192;

    // --- stage input patch (zero-padded at image borders) ---
    for (int p = t; p < IN2 * IN2; p += 256) {
        int r = p / IN2, cc = p - r * IN2;
        int iy = iy0 + r, ix = ix0 + cc;
        float v = 0.f;
        if (iy >= 0 && ix >= 0 && iy < 192 && ix < 192) v = cb[iy * 192 + ix];
        s_in[p] = v;
    }

    // thread -> 4 contiguous pixels: row ly, cols lx0..lx0+3
    const int ly = t >> 3;            // 0..31
    const int lx0 = (t & 7) * 4;      // 0,4,...,28
    float acc[NCH][4];
#pragma unroll
    for (int n = 0; n < NCH; ++n)
#pragma unroll
        for (int p = 0; p < 4; ++p) acc[n][p] = 0.f;

#pragma unroll 1
    for (int g = 0; g < NG; ++g) {
        __syncthreads();   // prev conv2 reads / staging done before overwrite

        // conv1 + relu for this group's 4 channels
        for (int p = t; p < HT2 * HT2; p += 256) {
            int r = p / HT2, cc = p - r * HT2;
            int hy = ty0 - 1 + r, hx = tx0 - 1 + cc;
            bool valid = (hy >= 0) && (hy < 96) && (hx >= 0) && (hx < 96);
            float in9[9];
#pragma unroll
            for (int q = 0; q < 9; ++q)
                in9[q] = s_in[(2 * r + q / 3) * IN2 + (2 * cc + q % 3)];
#pragma unroll
            for (int cl = 0; cl < CG; ++cl) {
                int c = g * CG + cl;
                float a = b1g[c];
#pragma unroll
                for (int q = 0; q < 9; ++q) a = fmaf(in9[q], W1g[q * C1 + c], a);
                a = valid ? fmaxf(a, 0.f) : 0.f;
                s_h[cl * (HT2 * HS) + r * HS + cc] = a;
            }
        }
        __syncthreads();

        // conv2 partial: per cl, 6 hrow LDS loads; weights from the packed
        // [c][k][n] table (contiguous per cl) via rotated s_load prefetch;
        // 612 register-only FMAs per cl.
#pragma unroll 1
        for (int cl = 0; cl < CG; ++cl) {
            float hrow[3][6];
            const float* hp = s_h + cl * (HT2 * HS) + ly * HS + lx0;
#pragma unroll
            for (int r = 0; r < 3; ++r) {
                float4 h4 = *(const float4*)(hp + r * HS);       // ds_read_b128
                float2 h2 = *(const float2*)(hp + r * HS + 4);   // ds_read_b64
                hrow[r][0] = h4.x; hrow[r][1] = h4.y;
                hrow[r][2] = h4.z; hrow[r][3] = h4.w;
                hrow[r][4] = h2.x; hrow[r][5] = h2.y;
            }
            const float* wbase = w2pack + (g * CG + cl) * KSTRIDE;
            float wc[NCH], wn[NCH];
#pragma unroll
            for (int n = 0; n < NCH; ++n) wc[n] = wbase[n];      // k=0
#pragma unroll
            for (int k = 0; k < 9; ++k) {
                const int ky = k / 3, kx = k - ky * 3;
                if (k < 8) {
                    const float* wnb = wbase + (k + 1) * NCH;    // contiguous
#pragma unroll
                    for (int n = 0; n < NCH; ++n) wn[n] = wnb[n]; // prefetch k+1
                }
#pragma unroll
                for (int n = 0; n < NCH; ++n)
#pragma unroll
                    for (int p = 0; p < 4; ++p)
                        acc[n][p] = fmaf(hrow[ky][kx + p], wc[n], acc[n][p]);
                if (k < 8) {
#pragma unroll
                    for (int n = 0; n < NCH; ++n) wc[n] = wn[n];  // rotate (s_mov)
                }
            }
        }
    }

    // --- per-channel argmax: in-thread max over 4 px (lowest-p tiebreak),
    // 32-bit fmax butterfly, ballot -> lowest equal lane (= lowest flat,
    // lane->flat monotone within wave), packed-u64 atomic for global order.
    const int yg = ty0 + ly, xg = tx0 + lx0;
    const unsigned fb = (unsigned)(yg * 96 + xg);
    const int lane = t & 63;
#pragma unroll
    for (int n = 0; n < NCH; ++n) {
        float bb = b2g[n];
        float best = acc[n][0] + bb;
        unsigned bf = fb;
#pragma unroll
        for (int p = 1; p < 4; ++p) {
            float v = acc[n][p] + bb;
            if (v > best) { best = v; bf = fb + p; }
        }
        float m = best;
#pragma unroll
        for (int off = 1; off < 64; off <<= 1)
            m = fmaxf(m, __shfl_xor(m, off, 64));
        unsigned long long eq = __ballot(best == m);
        if (lane == (int)(__ffsll(eq) - 1))
            atomicMax(&peaks[b * NCH + n], pack_key(best, bf));
    }
}

// One 64-lane wave per (b,n): decode peak, recompute 4 clipped neighbor cms
// values (b2 cancels in the sign differences), emit (x,y,val).
__global__ __launch_bounds__(64) void refine_kernel(
    const float* __restrict__ crops, const float* __restrict__ W1g,
    const float* __restrict__ b1g, const float* __restrict__ W2g,
    const unsigned long long* __restrict__ peaks, float* __restrict__ out) {
    const int bn = blockIdx.x;          // 0..128*17-1
    const int b = bn / NCH, n = bn % NCH;
    const int lane = threadIdx.x;

    unsigned long long pk = peaks[bn];
    unsigned key = (unsigned)(pk >> 32);
    unsigned fbits = (key & 0x80000000u) ? (key ^ 0x80000000u) : ~key;
    float val = __uint_as_float(fbits);
    int flat = (int)(~(unsigned)(pk & 0xffffffffu));
    int yi = flat / 96, xi = flat - yi * 96;

    // neighbor j: 0:(yi,xi+1) 1:(yi,xi-1) 2:(yi+1,xi) 3:(yi-1,xi), clipped
    const int j = lane >> 4;
    int yy = yi + ((j == 2) ? 1 : 0) - ((j == 3) ? 1 : 0);
    int xx = xi + ((j == 0) ? 1 : 0) - ((j == 1) ? 1 : 0);
    yy = min(max(yy, 0), 95);
    xx = min(max(xx, 0), 95);

    // hoist 7x7 crops patch: rows 2yy-2..2yy+4, cols 2xx-2..2xx+4
    const float* cb = crops + b * 192 * 192;
    float pat[7][7];
#pragma unroll
    for (int r = 0; r < 7; ++r) {
        int iy = 2 * yy - 2 + r;
#pragma unroll
        for (int s = 0; s < 7; ++s) {
            int ix = 2 * xx - 2 + s;
            pat[r][s] = (iy >= 0 && iy < 192 && ix >= 0 && ix < 192)
                            ? cb[iy * 192 + ix] : 0.f;
        }
    }

    float part = 0.f;
#pragma unroll
    for (int ci = 0; ci < 2; ++ci) {
        const int c = (lane & 15) + ci * 16;
        const float bias = b1g[c];
        float w1[9];
#pragma unroll
        for (int q = 0; q < 9; ++q) w1[q] = W1g[q * C1 + c];
#pragma unroll
        for (int dy = 0; dy < 3; ++dy) {
#pragma unroll
            for (int dx = 0; dx < 3; ++dx) {
                int hy = yy - 1 + dy, hx = xx - 1 + dx;
                if (hy >= 0 && hy < 96 && hx >= 0 && hx < 96) {
                    float a = bias;
#pragma unroll
                    for (int qy = 0; qy < 3; ++qy)
#pragma unroll
                        for (int qx = 0; qx < 3; ++qx)
                            a = fmaf(pat[2 * dy + qy][2 * dx + qx],
                                     w1[qy * 3 + qx], a);
                    float hval = fmaxf(a, 0.f);
                    part = fmaf(hval, W2g[((dy * 3 + dx) * C1 + c) * NCH + n], part);
                }
            }
        }
    }
    // sum the 16 lanes of each neighbor group
    for (int off = 8; off; off >>= 1) part += __shfl_down(part, off, 16);
    float g0 = __shfl(part, 0, 64);
    float g1 = __shfl(part, 16, 64);
    float g2 = __shfl(part, 32, 64);
    float g3 = __shfl(part, 48, 64);

    if (lane == 0) {
        float d0 = g0 - g1, d1 = g2 - g3;
        float sx = (d0 > 0.f) ? 1.f : ((d0 < 0.f) ? -1.f : 0.f);
        float sy = (d1 > 0.f) ? 1.f : ((d1 < 0.f) ? -1.f : 0.f);
        float px = ((float)xi + 0.25f * sx) * 2.f;
        float py = ((float)yi + 0.25f * sy) * 2.f;
        if (!(val >= 0.2f)) {
            px = __int_as_float(0x7fc00000);
            py = __int_as_float(0x7fc00000);
        }
        out[bn * 3 + 0] = px;
        out[bn * 3 + 1] = py;
        out[bn * 3 + 2] = val;
    }
}

extern "C" void kernel_launch(void* const* d_in, const int* in_sizes, int n_in,
                              void* d_out, int out_size, void* d_ws, size_t ws_size,
                              hipStream_t stream) {
    const float* crops = (const float*)d_in[0];
    const float* W1 = (const float*)d_in[1];
    const float* b1 = (const float*)d_in[2];
    const float* W2 = (const float*)d_in[3];
    const float* b2 = (const float*)d_in[4];
    float* out = (float*)d_out;
    unsigned long long* peaks = (unsigned long long*)d_ws;

    hipMemsetAsync(d_ws, 0, 128 * NCH * sizeof(unsigned long long), stream);

    repack_kernel<<<20, 256, 0, stream>>>(W2);   // ceil(4896/256)=20 (R11 bug: 19)

    dim3 gridB(9, 128);   // 3x3 tiles of 32x32 over 96x96, per image
    conv_peaks_kernel<<<gridB, 256, 0, stream>>>(crops, W1, b1, b2, peaks);
    refine_kernel<<<128 * NCH, 64, 0, stream>>>(crops, W1, b1, W2, peaks, out);
}

// Round 13
// 225.419 us; speedup vs baseline: 1.2675x; 1.2675x over previous
//
#include <hip/hip_runtime.h>

// FindInstancePeaks: fused conv backbone + global peak finding.
// crops (128,192,192,1) f32 -> conv1 3x3 s2 SAME (1->32) + relu
//                          -> conv2 3x3 s1 SAME (32->17) = cms (128,96,96,17)
// -> per (b,n): argmax over 96x96, quarter-pixel sign refine, *2, NaN<0.2.
//
// R13 = R8 byte-for-byte (174us conv: s_load weights, VGPR 52, spill-free)
// plus ONE change: per-block group-phase stagger. Co-resident blocks run
// identical code in lockstep -> all hit conv1/staging (low-FMA) and the 16
// barriers simultaneously, so no cross-block wave fills the SIMDs during
// drains. g = (gg + goff) & 7 puts co-resident blocks in different phases.
// (Channel-sum order changes -> ~1e-6 rounding delta, threshold 3.8.)
// Dead ends so far: LDS weights (R3/6/7 spill), packed-global weights
// (R12), k-rotation (R10), small tiles (R9), pk_fma (no fp32 2x on CDNA4),
// epilogue shuffle "conflicts" (R12: counter unchanged - not a cost).

#define NCH 17
#define C1 32
#define TS2 32          // cms tile (32x32)
#define HT2 34          // h rows/cols needed (tile+2)
#define HS 36           // s_h col stride (floats): 144 B rows, 16B-aligned
#define IN2 69          // input patch: 2*32+5
#define CG 4            // conv1 channels per group
#define NG 8            // groups

__device__ __forceinline__ unsigned long long pack_key(float v, unsigned flat) {
    unsigned ub = __float_as_uint(v);
    ub = (ub & 0x80000000u) ? ~ub : (ub | 0x80000000u);   // monotone float->uint
    return ((unsigned long long)ub << 32) | (unsigned)(~flat); // ~flat: ties -> lowest idx
}

__global__ __launch_bounds__(256, 4) void conv_peaks_kernel(
    const float* __restrict__ crops, const float* __restrict__ W1g,
    const float* __restrict__ b1g, const float* __restrict__ W2g,
    const float* __restrict__ b2g, unsigned long long* __restrict__ peaks) {
    __shared__ float s_in[IN2 * IN2];                        // 19044 B
    __shared__ __align__(16) float s_h[CG * HT2 * HS];       // 19584 B

    const int t = threadIdx.x;
    const int b = blockIdx.y;
    const int ty0 = (blockIdx.x / 3) * TS2;
    const int tx0 = (blockIdx.x % 3) * TS2;
    const int iy0 = 2 * ty0 - 2;
    const int ix0 = 2 * tx0 - 2;
    const float* cb = crops + b * 192 * 192;

    // phase stagger: co-resident blocks start at different groups
    const int goff = (blockIdx.x + blockIdx.y) & (NG - 1);

    // --- stage input patch (zero-padded at image borders) ---
    for (int p = t; p < IN2 * IN2; p += 256) {
        int r = p / IN2, cc = p - r * IN2;
        int iy = iy0 + r, ix = ix0 + cc;
        float v = 0.f;
        if (iy >= 0 && ix >= 0 && iy < 192 && ix < 192) v = cb[iy * 192 + ix];
        s_in[p] = v;
    }

    // thread -> 4 contiguous pixels: row ly, cols lx0..lx0+3
    const int ly = t >> 3;            // 0..31
    const int lx0 = (t & 7) * 4;      // 0,4,...,28
    float acc[NCH][4];
#pragma unroll
    for (int n = 0; n < NCH; ++n)
#pragma unroll
        for (int p = 0; p < 4; ++p) acc[n][p] = 0.f;

#pragma unroll 1
    for (int gg = 0; gg < NG; ++gg) {
        const int g = (gg + goff) & (NG - 1);
        __syncthreads();   // prev conv2 reads / staging done before overwrite

        // conv1 + relu for this group's 4 channels
        for (int p = t; p < HT2 * HT2; p += 256) {
            int r = p / HT2, cc = p - r * HT2;
            int hy = ty0 - 1 + r, hx = tx0 - 1 + cc;
            bool valid = (hy >= 0) && (hy < 96) && (hx >= 0) && (hx < 96);
            float in9[9];
#pragma unroll
            for (int q = 0; q < 9; ++q)
                in9[q] = s_in[(2 * r + q / 3) * IN2 + (2 * cc + q % 3)];
#pragma unroll
            for (int cl = 0; cl < CG; ++cl) {
                int c = g * CG + cl;
                float a = b1g[c];
#pragma unroll
                for (int q = 0; q < 9; ++q) a = fmaf(in9[q], W1g[q * C1 + c], a);
                a = valid ? fmaxf(a, 0.f) : 0.f;
                s_h[cl * (HT2 * HS) + r * HS + cc] = a;
            }
        }
        __syncthreads();

        // conv2 partial: per cl, load 3 h-rows x 6 floats once (LDS), read
        // W2 via uniform s_load (SGPRs - keeps VGPR pressure low), then
        // 612 register-only FMAs.  (R5/R8 proven body.)
#pragma unroll 1
        for (int cl = 0; cl < CG; ++cl) {
            float hrow[3][6];
            const float* hp = s_h + cl * (HT2 * HS) + ly * HS + lx0;
#pragma unroll
            for (int r = 0; r < 3; ++r) {
                float4 h4 = *(const float4*)(hp + r * HS);       // ds_read_b128
                float2 h2 = *(const float2*)(hp + r * HS + 4);   // ds_read_b64
                hrow[r][0] = h4.x; hrow[r][1] = h4.y;
                hrow[r][2] = h4.z; hrow[r][3] = h4.w;
                hrow[r][4] = h2.x; hrow[r][5] = h2.y;
            }
            const int c = g * CG + cl;
#pragma unroll
            for (int k = 0; k < 9; ++k) {
                const int ky = k / 3, kx = k - ky * 3;
                const float* wb = W2g + (k * C1 + c) * NCH;  // uniform -> s_load
                float w[NCH];
#pragma unroll
                for (int n = 0; n < NCH; ++n) w[n] = wb[n];
#pragma unroll
                for (int n = 0; n < NCH; ++n)
#pragma unroll
                    for (int p = 0; p < 4; ++p)
                        acc[n][p] = fmaf(hrow[ky][kx + p], w[n], acc[n][p]);
            }
        }
    }

    // --- per-channel argmax: in-thread max over 4 px, then wave reduce ---
    const int yg = ty0 + ly, xg = tx0 + lx0;
    const int lane = t & 63;
#pragma unroll
    for (int n = 0; n < NCH; ++n) {
        float bb = b2g[n];
        unsigned long long pk = pack_key(acc[n][0] + bb, (unsigned)(yg * 96 + xg));
#pragma unroll
        for (int p = 1; p < 4; ++p) {
            unsigned long long o = pack_key(acc[n][p] + bb, (unsigned)(yg * 96 + xg + p));
            if (o > pk) pk = o;
        }
#pragma unroll
        for (int off = 32; off; off >>= 1) {
            unsigned long long o = __shfl_down(pk, off, 64);
            if (o > pk) pk = o;
        }
        if (lane == 0) atomicMax(&peaks[b * NCH + n], pk);
    }
}

// One 64-lane wave per (b,n): decode peak, recompute 4 clipped neighbor cms
// values (b2 cancels in the sign differences), emit (x,y,val).
__global__ __launch_bounds__(64) void refine_kernel(
    const float* __restrict__ crops, const float* __restrict__ W1g,
    const float* __restrict__ b1g, const float* __restrict__ W2g,
    const unsigned long long* __restrict__ peaks, float* __restrict__ out) {
    const int bn = blockIdx.x;          // 0..128*17-1
    const int b = bn / NCH, n = bn % NCH;
    const int lane = threadIdx.x;

    unsigned long long pk = peaks[bn];
    unsigned key = (unsigned)(pk >> 32);
    unsigned fbits = (key & 0x80000000u) ? (key ^ 0x80000000u) : ~key;
    float val = __uint_as_float(fbits);
    int flat = (int)(~(unsigned)(pk & 0xffffffffu));
    int yi = flat / 96, xi = flat - yi * 96;

    // neighbor j: 0:(yi,xi+1) 1:(yi,xi-1) 2:(yi+1,xi) 3:(yi-1,xi), clipped
    const int j = lane >> 4;
    int yy = yi + ((j == 2) ? 1 : 0) - ((j == 3) ? 1 : 0);
    int xx = xi + ((j == 0) ? 1 : 0) - ((j == 1) ? 1 : 0);
    yy = min(max(yy, 0), 95);
    xx = min(max(xx, 0), 95);

    // hoist 7x7 crops patch: rows 2yy-2..2yy+4, cols 2xx-2..2xx+4
    const float* cb = crops + b * 192 * 192;
    float pat[7][7];
#pragma unroll
    for (int r = 0; r < 7; ++r) {
        int iy = 2 * yy - 2 + r;
#pragma unroll
        for (int s = 0; s < 7; ++s) {
            int ix = 2 * xx - 2 + s;
            pat[r][s] = (iy >= 0 && iy < 192 && ix >= 0 && ix < 192)
                            ? cb[iy * 192 + ix] : 0.f;
        }
    }

    float part = 0.f;
#pragma unroll
    for (int ci = 0; ci < 2; ++ci) {
        const int c = (lane & 15) + ci * 16;
        const float bias = b1g[c];
        float w1[9];
#pragma unroll
        for (int q = 0; q < 9; ++q) w1[q] = W1g[q * C1 + c];
#pragma unroll
        for (int dy = 0; dy < 3; ++dy) {
#pragma unroll
            for (int dx = 0; dx < 3; ++dx) {
                int hy = yy - 1 + dy, hx = xx - 1 + dx;
                if (hy >= 0 && hy < 96 && hx >= 0 && hx < 96) {
                    float a = bias;
#pragma unroll
                    for (int qy = 0; qy < 3; ++qy)
#pragma unroll
                        for (int qx = 0; qx < 3; ++qx)
                            a = fmaf(pat[2 * dy + qy][2 * dx + qx],
                                     w1[qy * 3 + qx], a);
                    float hval = fmaxf(a, 0.f);
                    part = fmaf(hval, W2g[((dy * 3 + dx) * C1 + c) * NCH + n], part);
                }
            }
        }
    }
    // sum the 16 lanes of each neighbor group
    for (int off = 8; off; off >>= 1) part += __shfl_down(part, off, 16);
    float g0 = __shfl(part, 0, 64);
    float g1 = __shfl(part, 16, 64);
    float g2 = __shfl(part, 32, 64);
    float g3 = __shfl(part, 48, 64);

    if (lane == 0) {
        float d0 = g0 - g1, d1 = g2 - g3;
        float sx = (d0 > 0.f) ? 1.f : ((d0 < 0.f) ? -1.f : 0.f);
        float sy = (d1 > 0.f) ? 1.f : ((d1 < 0.f) ? -1.f : 0.f);
        float px = ((float)xi + 0.25f * sx) * 2.f;
        float py = ((float)yi + 0.25f * sy) * 2.f;
        if (!(val >= 0.2f)) {
            px = __int_as_float(0x7fc00000);
            py = __int_as_float(0x7fc00000);
        }
        out[bn * 3 + 0] = px;
        out[bn * 3 + 1] = py;
        out[bn * 3 + 2] = val;
    }
}

extern "C" void kernel_launch(void* const* d_in, const int* in_sizes, int n_in,
                              void* d_out, int out_size, void* d_ws, size_t ws_size,
                              hipStream_t stream) {
    const float* crops = (const float*)d_in[0];
    const float* W1 = (const float*)d_in[1];
    const float* b1 = (const float*)d_in[2];
    const float* W2 = (const float*)d_in[3];
    const float* b2 = (const float*)d_in[4];
    float* out = (float*)d_out;
    unsigned long long* peaks = (unsigned long long*)d_ws;

    hipMemsetAsync(d_ws, 0, 128 * NCH * sizeof(unsigned long long), stream);

    dim3 gridB(9, 128);   // 3x3 tiles of 32x32 over 96x96, per image
    conv_peaks_kernel<<<gridB, 256, 0, stream>>>(crops, W1, b1, W2, b2, peaks);
    refine_kernel<<<128 * NCH, 64, 0, stream>>>(crops, W1, b1, W2, peaks, out);
}